// Round 5
// baseline (224.554 us; speedup 1.0000x reference)
//
#include <hip/hip_runtime.h>
#include <stdint.h>

#define Bb 8
#define Tt 1024
#define Cc 512
#define Hh 8
#define HD 64
#define MREL 68
#define NR 137           // 2*MREL+1
#define NRP 160          // k-extent padded to multiple of 32 for MFMA K-loop
#define A2S 168          // LDS row stride for S2/a2 union
#define SCALE 0.044194173824159216f     // 1/sqrt(512)  (ref scales by embed dim!)
#define KSCL  0.063763016845703125f     // SCALE * log2(e): exp(x)=exp2(x*log2e)

typedef unsigned short u16;
using u16x4  = __attribute__((ext_vector_type(4))) u16;
using u16x8  = __attribute__((ext_vector_type(8))) u16;
using f32x4  = __attribute__((ext_vector_type(4))) float;
using bf16x8 = __attribute__((ext_vector_type(8))) __bf16;

__device__ __forceinline__ u16 f2bf(float f) {
  uint32_t u = __builtin_bit_cast(uint32_t, f);
  u += 0x7FFF + ((u >> 16) & 1);       // RTNE
  return (u16)(u >> 16);
}
__device__ __forceinline__ float bf2f(u16 v) {
  return __builtin_bit_cast(float, (uint32_t)v << 16);
}
__device__ __forceinline__ bf16x8 as_bf8(u16x8 v) { return __builtin_bit_cast(bf16x8, v); }
__device__ __forceinline__ float fexp2(float x) {
  float r; asm("v_exp_f32 %0, %1" : "=v"(r) : "v"(x)); return r;
}

#define MFMA16(a, b, c) __builtin_amdgcn_mfma_f32_16x16x32_bf16((a), (b), (c), 0, 0, 0)
#define PSWZ(row, col) ((col) ^ (((row) & 7) << 3))

// ---------------------------------------------------------------------------
// Kernel 0a: transpose rel_v to bf16 [d][r] with zero pad.
// ---------------------------------------------------------------------------
__global__ __launch_bounds__(256) void relv_prep(
    const float* __restrict__ rel_v, u16* __restrict__ rvT)
{
  int i = blockIdx.x * 256 + threadIdx.x;
  if (i < HD * NRP) {
    int d = i / NRP, r = i - d * NRP;
    rvT[i] = (r < NR) ? f2bf(rel_v[r * HD + d]) : (u16)0;
  }
}

// ---------------------------------------------------------------------------
// Kernel 0b: convert the four 512x512 weights to bf16, TRANSPOSED [n][k].
// ---------------------------------------------------------------------------
__global__ __launch_bounds__(256) void w_prep(
    const float* __restrict__ Wq, const float* __restrict__ Wk,
    const float* __restrict__ Wv, const float* __restrict__ Wo,
    u16* __restrict__ WqT, u16* __restrict__ WkT,
    u16* __restrict__ WvT, u16* __restrict__ WoT)
{
  const float* W = blockIdx.y == 0 ? Wq : blockIdx.y == 1 ? Wk
                  : blockIdx.y == 2 ? Wv : Wo;
  u16* WT = blockIdx.y == 0 ? WqT : blockIdx.y == 1 ? WkT
           : blockIdx.y == 2 ? WvT : WoT;
  int i = blockIdx.x * 256 + threadIdx.x;   // over 512*128
  int n = i >> 7, k4 = (i & 127) * 4;
  u16x4 o;
  #pragma unroll
  for (int j = 0; j < 4; ++j) o[j] = f2bf(W[(size_t)(k4 + j) * Cc + n]);
  *(u16x4*)&WT[(size_t)n * Cc + k4] = o;
}

// ---------------------------------------------------------------------------
// Kernel 1: fused QKV projection.  x (8192x512 f32) @ {Wq,Wk,Wv} + bias.
// Q,K written bf16 (B,H,T,HD); V written TRANSPOSED bf16 (B,H,HD,T).
// ---------------------------------------------------------------------------
__global__ __launch_bounds__(256) void qkv_gemm(
    const float* __restrict__ x,
    const u16* __restrict__ WqT, const u16* __restrict__ WkT,
    const u16* __restrict__ WvT,
    const float* __restrict__ bq, const float* __restrict__ bk,
    const float* __restrict__ bv,
    u16* __restrict__ Qb, u16* __restrict__ Kb, u16* __restrict__ VTb)
{
  __shared__ u16 Xs[64][40];
  __shared__ u16 WTs[3][64][40];

  const u16* Wp[3] = {WqT, WkT, WvT};
  const float* bp[3] = {bq, bk, bv};

  const int tid = threadIdx.x;
  const int wv_ = tid >> 6;
  const int l   = tid & 63;
  const int lr  = l & 15, lg = l >> 4;
  const int m0  = blockIdx.x * 64;
  const int n0  = blockIdx.y * 64;
  const int srow = tid >> 2, scol = (tid & 3) * 8;

  f32x4 acc[3][4];
  #pragma unroll
  for (int a = 0; a < 3; ++a)
    #pragma unroll
    for (int b = 0; b < 4; ++b) acc[a][b] = (f32x4){0.f, 0.f, 0.f, 0.f};

  for (int k0 = 0; k0 < Cc; k0 += 32) {
    {
      const float* xp = x + (size_t)(m0 + srow) * Cc + k0 + scol;
      f32x4 v0 = *(const f32x4*)xp;
      f32x4 v1 = *(const f32x4*)(xp + 4);
      u16x8 o = {f2bf(v0[0]), f2bf(v0[1]), f2bf(v0[2]), f2bf(v0[3]),
                 f2bf(v1[0]), f2bf(v1[1]), f2bf(v1[2]), f2bf(v1[3])};
      *(u16x8*)&Xs[srow][scol] = o;
    }
    #pragma unroll
    for (int q3 = 0; q3 < 3; ++q3) {
      u16x8 w = *(const u16x8*)(Wp[q3] + (size_t)(n0 + srow) * Cc + k0 + scol);
      *(u16x8*)&WTs[q3][srow][scol] = w;
    }
    __syncthreads();

    bf16x8 a = as_bf8(*(const u16x8*)&Xs[wv_ * 16 + lr][lg * 8]);
    #pragma unroll
    for (int q3 = 0; q3 < 3; ++q3) {
      #pragma unroll
      for (int nt = 0; nt < 4; ++nt) {
        bf16x8 b = as_bf8(*(const u16x8*)&WTs[q3][nt * 16 + lr][lg * 8]);
        acc[q3][nt] = MFMA16(a, b, acc[q3][nt]);
      }
    }
    __syncthreads();
  }

  const int bidx = m0 >> 10;
  #pragma unroll
  for (int q3 = 0; q3 < 3; ++q3) {
    #pragma unroll
    for (int nt = 0; nt < 4; ++nt) {
      int n = n0 + nt * 16 + lr;
      int h = n >> 6, d = n & 63;
      float bias = bp[q3][n];
      #pragma unroll
      for (int i = 0; i < 4; ++i) {
        int m = m0 + wv_ * 16 + lg * 4 + i;
        int t = m & (Tt - 1);
        u16 o = f2bf(acc[q3][nt][i] + bias);
        size_t bh = (size_t)(bidx * Hh + h);
        if (q3 == 0)      Qb[(bh * Tt + t) * HD + d] = o;
        else if (q3 == 1) Kb[(bh * Tt + t) * HD + d] = o;
        else              VTb[(bh * HD + d) * Tt + t] = o;
      }
    }
  }
}

// ---------------------------------------------------------------------------
// Kernel 2: relative attention. One block = one (b,h) x 16 q-rows.
// Register-double-buffered K (Phase A) and V (Phase D) pipelines, 2 tiles
// deep (4 loads in flight). bh is the FAST grid dim -> XCD = bh%8, K/V of
// each bh stays in one XCD's L2 (2MB/XCD footprint).
// ---------------------------------------------------------------------------
__global__ __launch_bounds__(256) void attn_kernel(
    const u16* __restrict__ Qb, const u16* __restrict__ Kb,
    const u16* __restrict__ VTb, const u16* __restrict__ rvT,
    const float* __restrict__ rel_k,
    u16* __restrict__ AO)
{
  __shared__ u16 P[16][1024];      // exp'd probs, bf16, XOR-swizzled cols
  __shared__ u16 S2a2[16][A2S];    // Phase A: S2*KSCL; Phase C+: a2
  __shared__ float red[2][4][16];  // per-wave partials: [0]=rowsum, [1]=s0
  __shared__ float rowrcp[16];

  const int tid = threadIdx.x;
  const int wv_ = tid >> 6, l = tid & 63;
  const int lr = l & 15, lg = l >> 4;
  const int bh = blockIdx.x;           // FAST dim -> XCD = bh % 8
  const int q0 = blockIdx.y * 16;
  const int bidx = bh >> 3, h = bh & 7;

  const u16* Qh = Qb  + (size_t)bh * Tt * HD;
  const u16* Kh = Kb  + (size_t)bh * Tt * HD;
  const u16* Vh = VTb + (size_t)bh * HD * Tt;

  // Q fragments (held for the whole block)
  bf16x8 aQ0 = as_bf8(*(const u16x8*)(Qh + (size_t)(q0 + lr) * HD + lg * 8));
  bf16x8 aQ1 = as_bf8(*(const u16x8*)(Qh + (size_t)(q0 + lr) * HD + 32 + lg * 8));

  // Early preload: K pair 0 (latency hides under the S2 phase)
  const u16* kbase = Kh + (size_t)(wv_ * 16 + lr) * HD + lg * 8;
  u16x8 cb0[2], cb1[2];
  cb0[0] = *(const u16x8*)(kbase);
  cb1[0] = *(const u16x8*)(kbase + 32);
  cb0[1] = *(const u16x8*)(kbase + (size_t)64 * HD);
  cb1[1] = *(const u16x8*)(kbase + (size_t)64 * HD + 32);

  // S2'' = (Q @ rel_k^T) * SCALE * log2e
  for (int ct = wv_; ct < 9; ct += 4) {
    int r = ct * 16 + lr;
    f32x4 acc = {0.f, 0.f, 0.f, 0.f};
    #pragma unroll
    for (int d0 = 0; d0 < 64; d0 += 32) {
      u16x8 bbits = {0, 0, 0, 0, 0, 0, 0, 0};
      if (r < NR) {
        f32x4 v0 = *(const f32x4*)(rel_k + (size_t)r * HD + d0 + lg * 8);
        f32x4 v1 = *(const f32x4*)(rel_k + (size_t)r * HD + d0 + lg * 8 + 4);
        bbits = (u16x8){f2bf(v0[0]), f2bf(v0[1]), f2bf(v0[2]), f2bf(v0[3]),
                        f2bf(v1[0]), f2bf(v1[1]), f2bf(v1[2]), f2bf(v1[3])};
      }
      acc = MFMA16(d0 ? aQ1 : aQ0, as_bf8(bbits), acc);
    }
    #pragma unroll
    for (int i = 0; i < 4; ++i)
      S2a2[lg * 4 + i][ct * 16 + lr] = f2bf(acc[i] * KSCL);
  }
  __syncthreads();

  // Phase A: P = exp2(QK^T*KSCL + S2''), rowsum + s0 partials.
  // Pipelined: 8 pair-steps, next pair (4 loads) prefetched during compute.
  float ps[4]  = {0.f, 0.f, 0.f, 0.f};
  float ps0[4] = {0.f, 0.f, 0.f, 0.f};

  auto tileA = [&](int kt, u16x8 b0, u16x8 b1) {
    int kc = kt * 64 + wv_ * 16 + lr;
    f32x4 acc = {0.f, 0.f, 0.f, 0.f};
    acc = MFMA16(aQ0, as_bf8(b0), acc);
    acc = MFMA16(aQ1, as_bf8(b1), acc);
    int b2 = kc - q0 - lg * 4;     // dr for element i is b2 - i
    #pragma unroll
    for (int i = 0; i < 4; ++i) {
      int row = lg * 4 + i;
      int dr = b2 - i;
      dr = dr < -MREL ? -MREL : (dr > MREL ? MREL : dr);
      float p = fexp2(fmaf(acc[i], KSCL, bf2f(S2a2[row][dr + MREL])));
      ps[i] += p;
      if (kc <= q0 + row - MREL) ps0[i] += p;
      P[row][PSWZ(row, kc)] = f2bf(p);
    }
  };

  for (int kp = 0; kp < 7; ++kp) {
    u16x8 nb0[2], nb1[2];
    const u16* p0 = kbase + (size_t)(kp * 2 + 2) * 64 * HD;
    const u16* p1 = kbase + (size_t)(kp * 2 + 3) * 64 * HD;
    nb0[0] = *(const u16x8*)(p0);
    nb1[0] = *(const u16x8*)(p0 + 32);
    nb0[1] = *(const u16x8*)(p1);
    nb1[1] = *(const u16x8*)(p1 + 32);
    tileA(kp * 2,     cb0[0], cb1[0]);
    tileA(kp * 2 + 1, cb0[1], cb1[1]);
    cb0[0] = nb0[0]; cb1[0] = nb1[0];
    cb0[1] = nb0[1]; cb1[1] = nb1[1];
  }
  tileA(14, cb0[0], cb1[0]);
  tileA(15, cb0[1], cb1[1]);

  #pragma unroll
  for (int off = 1; off < 16; off <<= 1) {
    #pragma unroll
    for (int i = 0; i < 4; ++i) {
      ps[i]  += __shfl_xor(ps[i], off);
      ps0[i] += __shfl_xor(ps0[i], off);
    }
  }
  if (lr == 0) {
    #pragma unroll
    for (int i = 0; i < 4; ++i) {
      red[0][wv_][lg * 4 + i] = ps[i];
      red[1][wv_][lg * 4 + i] = ps0[i];
    }
  }

  // Early preload for Phase D: first V pair + all 5 rel_v fragments
  // (latency hides under the reduction barrier + Phase C).
  const u16* vrow = Vh + (size_t)(wv_ * 16 + lr) * Tt + lg * 8;
  u16x8 vc0 = *(const u16x8*)(vrow);
  u16x8 vc1 = *(const u16x8*)(vrow + 32);
  u16x8 br[5];
  #pragma unroll
  for (int j = 0; j < 5; ++j)
    br[j] = *(const u16x8*)(rvT + (size_t)(wv_ * 16 + lr) * NRP + j * 32 + lg * 8);

  __syncthreads();

  // Phase C: a2 (overwrites S2''). Interior = shifted copy of P + band sum;
  // a2[0] = s0; a2[136] = rowsum - s0 - band; pads zeroed.
  {
    int row = tid >> 4, c16 = tid & 15;
    int qg = q0 + row;
    float band = 0.f;
    for (int r = 1 + c16; r < NR - 1; r += 16) {
      int k = qg + r - MREL;
      u16 v = (k >= 0 && k < Tt) ? P[row][PSWZ(row, k)] : (u16)0;
      S2a2[row][r] = v;
      band += bf2f(v);
    }
    #pragma unroll
    for (int off = 1; off < 16; off <<= 1) band += __shfl_xor(band, off);
    for (int r = NR + c16; r < NRP; r += 16) S2a2[row][r] = 0;
    if (c16 == 0) {
      float t0 = red[0][0][row] + red[0][1][row] + red[0][2][row] + red[0][3][row];
      float t1 = red[1][0][row] + red[1][1][row] + red[1][2][row] + red[1][3][row];
      S2a2[row][0]      = f2bf(t1);
      S2a2[row][NR - 1] = f2bf(t0 - t1 - band);
      rowrcp[row] = 1.0f / t0;
    }
  }
  __syncthreads();

  // Phase D: O = (P @ V + a2 @ rel_v) * rowrcp.  Pipelined V, 2 accumulators.
  f32x4 o0 = {0.f, 0.f, 0.f, 0.f}, o1 = {0.f, 0.f, 0.f, 0.f};
  for (int kp = 0; kp < 15; ++kp) {
    u16x8 vn0 = *(const u16x8*)(vrow + kp * 64 + 64);
    u16x8 vn1 = *(const u16x8*)(vrow + kp * 64 + 96);
    bf16x8 a0 = as_bf8(*(const u16x8*)&P[lr][PSWZ(lr, kp * 64 + lg * 8)]);
    bf16x8 a1 = as_bf8(*(const u16x8*)&P[lr][PSWZ(lr, kp * 64 + 32 + lg * 8)]);
    o0 = MFMA16(a0, as_bf8(vc0), o0);
    o1 = MFMA16(a1, as_bf8(vc1), o1);
    vc0 = vn0; vc1 = vn1;
  }
  {
    bf16x8 a0 = as_bf8(*(const u16x8*)&P[lr][PSWZ(lr, 15 * 64 + lg * 8)]);
    bf16x8 a1 = as_bf8(*(const u16x8*)&P[lr][PSWZ(lr, 15 * 64 + 32 + lg * 8)]);
    o0 = MFMA16(a0, as_bf8(vc0), o0);
    o1 = MFMA16(a1, as_bf8(vc1), o1);
  }
  #pragma unroll
  for (int j = 0; j < 5; ++j) {
    bf16x8 aa = as_bf8(*(const u16x8*)&S2a2[lr][j * 32 + lg * 8]);
    if (j & 1) o1 = MFMA16(aa, as_bf8(br[j]), o1);
    else       o0 = MFMA16(aa, as_bf8(br[j]), o0);
  }

  #pragma unroll
  for (int i = 0; i < 4; ++i) {
    int row = lg * 4 + i;
    float val = (o0[i] + o1[i]) * rowrcp[row];
    int t = q0 + row, cc = h * HD + wv_ * 16 + lr;
    AO[((size_t)(bidx * Tt + t)) * Cc + cc] = f2bf(val);
  }
}

// ---------------------------------------------------------------------------
// Kernel 3: output projection.  AO (bf16 8192x512) @ Wo + bo -> f32 d_out.
// ---------------------------------------------------------------------------
__global__ __launch_bounds__(256) void out_gemm(
    const u16* __restrict__ AO, const u16* __restrict__ WoT,
    const float* __restrict__ bo, float* __restrict__ out)
{
  __shared__ u16 As[64][40];
  __shared__ u16 WTs[64][40];
  const int tid = threadIdx.x;
  const int wv_ = tid >> 6, l = tid & 63, lr = l & 15, lg = l >> 4;
  const int m0 = blockIdx.x * 64, n0 = blockIdx.y * 64;
  const int srow = tid >> 2, scol = (tid & 3) * 8;

  f32x4 acc[4];
  #pragma unroll
  for (int b = 0; b < 4; ++b) acc[b] = (f32x4){0.f, 0.f, 0.f, 0.f};

  for (int k0 = 0; k0 < Cc; k0 += 32) {
    u16x8 av = *(const u16x8*)(AO + (size_t)(m0 + srow) * Cc + k0 + scol);
    *(u16x8*)&As[srow][scol] = av;
    u16x8 wv2 = *(const u16x8*)(WoT + (size_t)(n0 + srow) * Cc + k0 + scol);
    *(u16x8*)&WTs[srow][scol] = wv2;
    __syncthreads();

    bf16x8 a = as_bf8(*(const u16x8*)&As[wv_ * 16 + lr][lg * 8]);
    #pragma unroll
    for (int nt = 0; nt < 4; ++nt) {
      bf16x8 b = as_bf8(*(const u16x8*)&WTs[nt * 16 + lr][lg * 8]);
      acc[nt] = MFMA16(a, b, acc[nt]);
    }
    __syncthreads();
  }

  #pragma unroll
  for (int nt = 0; nt < 4; ++nt) {
    int n = n0 + nt * 16 + lr;
    float bias = bo[n];
    #pragma unroll
    for (int i = 0; i < 4; ++i) {
      int m = m0 + wv_ * 16 + lg * 4 + i;
      out[(size_t)m * Cc + n] = acc[nt][i] + bias;
    }
  }
}

// ---------------------------------------------------------------------------
extern "C" void kernel_launch(void* const* d_in, const int* in_sizes, int n_in,
                              void* d_out, int out_size, void* d_ws, size_t ws_size,
                              hipStream_t stream) {
  const float* x  = (const float*)d_in[0];
  const float* Wq = (const float*)d_in[1];
  const float* bq = (const float*)d_in[2];
  const float* Wk = (const float*)d_in[3];
  const float* bk = (const float*)d_in[4];
  const float* Wv = (const float*)d_in[5];
  const float* bv = (const float*)d_in[6];
  const float* Wo = (const float*)d_in[7];
  const float* bo = (const float*)d_in[8];
  const float* rk = (const float*)d_in[9];
  const float* rv = (const float*)d_in[10];

  const size_t BHTD = (size_t)Bb * Hh * Tt * HD;   // 4,194,304 elements
  const size_t WSZ  = (size_t)Cc * Cc;             // 262,144

  // d_out scratch: Q,K bf16 (fully consumed before out_gemm overwrites).
  u16* Qb = (u16*)d_out;
  u16* Kb = Qb + BHTD;
  // d_ws layout (u16 units): VT | AO | rvT | WqT | WkT | WvT | WoT  (~19MB)
  u16* VT  = (u16*)d_ws;
  u16* AO  = VT + BHTD;
  u16* rvT = AO + BHTD;
  u16* WqT = rvT + (size_t)HD * NRP;
  u16* WkT = WqT + WSZ;
  u16* WvT = WkT + WSZ;
  u16* WoT = WvT + WSZ;
  float* outf = (float*)d_out;

  relv_prep<<<dim3((HD * NRP + 255) / 256), 256, 0, stream>>>(rv, rvT);
  w_prep<<<dim3(256, 4), 256, 0, stream>>>(Wq, Wk, Wv, Wo, WqT, WkT, WvT, WoT);
  qkv_gemm<<<dim3(128, 8), 256, 0, stream>>>(x, WqT, WkT, WvT, bq, bk, bv, Qb, Kb, VT);
  // bh on the FAST grid dim: XCD = bh % 8 (L2 locality for K/V)
  attn_kernel<<<dim3(64, 64), 256, 0, stream>>>(Qb, Kb, VT, rvT, rk, AO);
  out_gemm<<<dim3(128, 8), 256, 0, stream>>>(AO, WoT, bo, outf);
}

// Round 7
// 209.563 us; speedup vs baseline: 1.0715x; 1.0715x over previous
//
#include <hip/hip_runtime.h>
#include <stdint.h>

#define Bb 8
#define Tt 1024
#define Cc 512
#define Hh 8
#define HD 64
#define MREL 68
#define NR 137           // 2*MREL+1
#define NRP 160          // k-extent padded to multiple of 32 for MFMA K-loop
#define A2S 168          // LDS row stride for S2/a2 union
#define SCALE 0.044194173824159216f     // 1/sqrt(512)  (ref scales by embed dim!)
#define KSCL  0.063763016845703125f     // SCALE * log2(e): exp(x)=exp2(x*log2e)

typedef unsigned short u16;
typedef unsigned int u32;
using u16x4  = __attribute__((ext_vector_type(4))) u16;
using u16x8  = __attribute__((ext_vector_type(8))) u16;
using f32x4  = __attribute__((ext_vector_type(4))) float;
using bf16x8 = __attribute__((ext_vector_type(8))) __bf16;

__device__ __forceinline__ u16 f2bf(float f) {
  u32 u = __builtin_bit_cast(u32, f);
  u += 0x7FFF + ((u >> 16) & 1);       // RTNE
  return (u16)(u >> 16);
}
__device__ __forceinline__ float bf2f(u16 v) {
  return __builtin_bit_cast(float, (u32)v << 16);
}
__device__ __forceinline__ bf16x8 as_bf8(u16x8 v) { return __builtin_bit_cast(bf16x8, v); }
__device__ __forceinline__ float fexp2(float x) {
  float r; asm("v_exp_f32 %0, %1" : "=v"(r) : "v"(x)); return r;
}

#define MFMA16(a, b, c) __builtin_amdgcn_mfma_f32_16x16x32_bf16((a), (b), (c), 0, 0, 0)
#define PSWZ(row, col) ((col) ^ (((row) & 7) << 3))

// ---------------------------------------------------------------------------
// Kernel 0a: transpose rel_v to bf16 [d][r] with zero pad.
// ---------------------------------------------------------------------------
__global__ __launch_bounds__(256) void relv_prep(
    const float* __restrict__ rel_v, u16* __restrict__ rvT)
{
  int i = blockIdx.x * 256 + threadIdx.x;
  if (i < HD * NRP) {
    int d = i / NRP, r = i - d * NRP;
    rvT[i] = (r < NR) ? f2bf(rel_v[r * HD + d]) : (u16)0;
  }
}

// ---------------------------------------------------------------------------
// Kernel 0b: convert the four 512x512 weights to bf16, TRANSPOSED [n][k].
// ---------------------------------------------------------------------------
__global__ __launch_bounds__(256) void w_prep(
    const float* __restrict__ Wq, const float* __restrict__ Wk,
    const float* __restrict__ Wv, const float* __restrict__ Wo,
    u16* __restrict__ WqT, u16* __restrict__ WkT,
    u16* __restrict__ WvT, u16* __restrict__ WoT)
{
  const float* W = blockIdx.y == 0 ? Wq : blockIdx.y == 1 ? Wk
                  : blockIdx.y == 2 ? Wv : Wo;
  u16* WT = blockIdx.y == 0 ? WqT : blockIdx.y == 1 ? WkT
           : blockIdx.y == 2 ? WvT : WoT;
  int i = blockIdx.x * 256 + threadIdx.x;   // over 512*128
  int n = i >> 7, k4 = (i & 127) * 4;
  u16x4 o;
  #pragma unroll
  for (int j = 0; j < 4; ++j) o[j] = f2bf(W[(size_t)(k4 + j) * Cc + n]);
  *(u16x4*)&WT[(size_t)n * Cc + k4] = o;
}

// ---------------------------------------------------------------------------
// Kernel 1: fused QKV projection.  x (8192x512 f32) @ {Wq,Wk,Wv} + bias.
// Q,K written bf16 (B,H,T,HD); V written TRANSPOSED bf16 (B,H,HD,T).
// ---------------------------------------------------------------------------
__global__ __launch_bounds__(256) void qkv_gemm(
    const float* __restrict__ x,
    const u16* __restrict__ WqT, const u16* __restrict__ WkT,
    const u16* __restrict__ WvT,
    const float* __restrict__ bq, const float* __restrict__ bk,
    const float* __restrict__ bv,
    u16* __restrict__ Qb, u16* __restrict__ Kb, u16* __restrict__ VTb)
{
  __shared__ u16 Xs[64][40];
  __shared__ u16 WTs[3][64][40];

  const u16* Wp[3] = {WqT, WkT, WvT};
  const float* bp[3] = {bq, bk, bv};

  const int tid = threadIdx.x;
  const int wv_ = tid >> 6;
  const int l   = tid & 63;
  const int lr  = l & 15, lg = l >> 4;
  const int m0  = blockIdx.x * 64;
  const int n0  = blockIdx.y * 64;
  const int srow = tid >> 2, scol = (tid & 3) * 8;

  f32x4 acc[3][4];
  #pragma unroll
  for (int a = 0; a < 3; ++a)
    #pragma unroll
    for (int b = 0; b < 4; ++b) acc[a][b] = (f32x4){0.f, 0.f, 0.f, 0.f};

  for (int k0 = 0; k0 < Cc; k0 += 32) {
    {
      const float* xp = x + (size_t)(m0 + srow) * Cc + k0 + scol;
      f32x4 v0 = *(const f32x4*)xp;
      f32x4 v1 = *(const f32x4*)(xp + 4);
      u16x8 o = {f2bf(v0[0]), f2bf(v0[1]), f2bf(v0[2]), f2bf(v0[3]),
                 f2bf(v1[0]), f2bf(v1[1]), f2bf(v1[2]), f2bf(v1[3])};
      *(u16x8*)&Xs[srow][scol] = o;
    }
    #pragma unroll
    for (int q3 = 0; q3 < 3; ++q3) {
      u16x8 w = *(const u16x8*)(Wp[q3] + (size_t)(n0 + srow) * Cc + k0 + scol);
      *(u16x8*)&WTs[q3][srow][scol] = w;
    }
    __syncthreads();

    bf16x8 a = as_bf8(*(const u16x8*)&Xs[wv_ * 16 + lr][lg * 8]);
    #pragma unroll
    for (int q3 = 0; q3 < 3; ++q3) {
      #pragma unroll
      for (int nt = 0; nt < 4; ++nt) {
        bf16x8 b = as_bf8(*(const u16x8*)&WTs[q3][nt * 16 + lr][lg * 8]);
        acc[q3][nt] = MFMA16(a, b, acc[q3][nt]);
      }
    }
    __syncthreads();
  }

  const int bidx = m0 >> 10;
  #pragma unroll
  for (int q3 = 0; q3 < 3; ++q3) {
    #pragma unroll
    for (int nt = 0; nt < 4; ++nt) {
      int n = n0 + nt * 16 + lr;
      int h = n >> 6, d = n & 63;
      float bias = bp[q3][n];
      #pragma unroll
      for (int i = 0; i < 4; ++i) {
        int m = m0 + wv_ * 16 + lg * 4 + i;
        int t = m & (Tt - 1);
        u16 o = f2bf(acc[q3][nt][i] + bias);
        size_t bh = (size_t)(bidx * Hh + h);
        if (q3 == 0)      Qb[(bh * Tt + t) * HD + d] = o;
        else if (q3 == 1) Kb[(bh * Tt + t) * HD + d] = o;
        else              VTb[(bh * HD + d) * Tt + t] = o;
      }
    }
  }
}

// ---------------------------------------------------------------------------
// Kernel 2: relative attention. One block = one (b,h) x 16 q-rows.
// R4 structure (VGPR-lean, occupancy 4 blocks/CU) + XCD swizzle (bh fast
// grid dim -> K/V L2-resident per XCD) + fully-unrolled Phase A with
// depth-1 K prefetch (uniform clamped S2 gather, no region split).
// ---------------------------------------------------------------------------
__global__ __launch_bounds__(256, 4) void attn_kernel(
    const u16* __restrict__ Qb, const u16* __restrict__ Kb,
    const u16* __restrict__ VTb, const u16* __restrict__ rvT,
    const float* __restrict__ rel_k,
    u16* __restrict__ AO)
{
  __shared__ u16 P[16][1024];      // exp'd probs, bf16, XOR-swizzled cols
  __shared__ u16 S2a2[16][A2S];    // Phase A: S2*KSCL; Phase C+: a2
  __shared__ float red[2][4][16];  // per-wave partials: [0]=rowsum, [1]=s0
  __shared__ float rowrcp[16];

  const int tid = threadIdx.x;
  const int wv_ = tid >> 6, l = tid & 63;
  const int lr = l & 15, lg = l >> 4;
  const int bh = blockIdx.x;           // FAST dim -> XCD = bh % 8
  const int q0 = blockIdx.y * 16;
  const int bidx = bh >> 3, h = bh & 7;

  const u16* Qh = Qb  + (size_t)bh * Tt * HD;
  const u16* Kh = Kb  + (size_t)bh * Tt * HD;
  const u16* Vh = VTb + (size_t)bh * HD * Tt;

  // Q fragments (held for the whole block)
  bf16x8 aQ0 = as_bf8(*(const u16x8*)(Qh + (size_t)(q0 + lr) * HD + lg * 8));
  bf16x8 aQ1 = as_bf8(*(const u16x8*)(Qh + (size_t)(q0 + lr) * HD + 32 + lg * 8));

  // Early K preload for tile 0 (latency hides under the S2 phase)
  const u16* kbase = Kh + (size_t)(wv_ * 16 + lr) * HD + lg * 8;
  u16x8 c0 = *(const u16x8*)(kbase);
  u16x8 c1 = *(const u16x8*)(kbase + 32);

  // S2'' = (Q @ rel_k^T) * SCALE * log2e
  for (int ct = wv_; ct < 9; ct += 4) {
    int r = ct * 16 + lr;
    f32x4 acc = {0.f, 0.f, 0.f, 0.f};
    #pragma unroll
    for (int d0 = 0; d0 < 64; d0 += 32) {
      u16x8 bbits = {0, 0, 0, 0, 0, 0, 0, 0};
      if (r < NR) {
        f32x4 v0 = *(const f32x4*)(rel_k + (size_t)r * HD + d0 + lg * 8);
        f32x4 v1 = *(const f32x4*)(rel_k + (size_t)r * HD + d0 + lg * 8 + 4);
        bbits = (u16x8){f2bf(v0[0]), f2bf(v0[1]), f2bf(v0[2]), f2bf(v0[3]),
                        f2bf(v1[0]), f2bf(v1[1]), f2bf(v1[2]), f2bf(v1[3])};
      }
      acc = MFMA16(d0 ? aQ1 : aQ0, as_bf8(bbits), acc);
    }
    #pragma unroll
    for (int i = 0; i < 4; ++i)
      S2a2[lg * 4 + i][ct * 16 + lr] = f2bf(acc[i] * KSCL);
  }
  __syncthreads();

  // Phase A: P = exp2(QK^T*KSCL + S2''), rowsum + s0 partials.
  // Fully unrolled, depth-1 K prefetch (2 loads in flight).
  float ps[4]  = {0.f, 0.f, 0.f, 0.f};
  float ps0[4] = {0.f, 0.f, 0.f, 0.f};

  #pragma unroll
  for (int kt = 0; kt < 16; ++kt) {
    u16x8 n0{}, n1{};
    if (kt < 15) {
      n0 = *(const u16x8*)(kbase + (size_t)(kt + 1) * 64 * HD);
      n1 = *(const u16x8*)(kbase + (size_t)(kt + 1) * 64 * HD + 32);
    }
    int kc = kt * 64 + wv_ * 16 + lr;
    f32x4 acc = {0.f, 0.f, 0.f, 0.f};
    acc = MFMA16(aQ0, as_bf8(c0), acc);
    acc = MFMA16(aQ1, as_bf8(c1), acc);
    int b2 = kc - q0 - lg * 4;     // dr for element i is b2 - i
    #pragma unroll
    for (int i = 0; i < 4; ++i) {
      int row = lg * 4 + i;
      int dr = b2 - i;
      dr = dr < -MREL ? -MREL : (dr > MREL ? MREL : dr);
      float p = fexp2(fmaf(acc[i], KSCL, bf2f(S2a2[row][dr + MREL])));
      ps[i] += p;
      if (kc <= q0 + row - MREL) ps0[i] += p;
      P[row][PSWZ(row, kc)] = f2bf(p);
    }
    if (kt < 15) { c0 = n0; c1 = n1; }
  }

  #pragma unroll
  for (int off = 1; off < 16; off <<= 1) {
    #pragma unroll
    for (int i = 0; i < 4; ++i) {
      ps[i]  += __shfl_xor(ps[i], off);
      ps0[i] += __shfl_xor(ps0[i], off);
    }
  }
  if (lr == 0) {
    #pragma unroll
    for (int i = 0; i < 4; ++i) {
      red[0][wv_][lg * 4 + i] = ps[i];
      red[1][wv_][lg * 4 + i] = ps0[i];
    }
  }

  // Early preload of the first V pair (hides under reduction + Phase C)
  const u16* vrow = Vh + (size_t)(wv_ * 16 + lr) * Tt + lg * 8;
  u16x8 vc0 = *(const u16x8*)(vrow);
  u16x8 vc1 = *(const u16x8*)(vrow + 32);

  __syncthreads();

  // Phase C: a2 (overwrites S2''). Interior = shifted copy of P + band sum;
  // a2[0] = s0; a2[136] = rowsum - s0 - band; pads zeroed.
  {
    int row = tid >> 4, c16 = tid & 15;
    int qg = q0 + row;
    float band = 0.f;
    for (int r = 1 + c16; r < NR - 1; r += 16) {
      int k = qg + r - MREL;
      u16 v = (k >= 0 && k < Tt) ? P[row][PSWZ(row, k)] : (u16)0;
      S2a2[row][r] = v;
      band += bf2f(v);
    }
    #pragma unroll
    for (int off = 1; off < 16; off <<= 1) band += __shfl_xor(band, off);
    for (int r = NR + c16; r < NRP; r += 16) S2a2[row][r] = 0;
    if (c16 == 0) {
      float t0 = red[0][0][row] + red[0][1][row] + red[0][2][row] + red[0][3][row];
      float t1 = red[1][0][row] + red[1][1][row] + red[1][2][row] + red[1][3][row];
      S2a2[row][0]      = f2bf(t1);
      S2a2[row][NR - 1] = f2bf(t0 - t1 - band);
      rowrcp[row] = 1.0f / t0;
    }
  }
  __syncthreads();

  // Phase D: O = (P @ V + a2 @ rel_v) * rowrcp. Depth-1 V pipeline, 2 accs.
  f32x4 o0 = {0.f, 0.f, 0.f, 0.f}, o1 = {0.f, 0.f, 0.f, 0.f};
  #pragma unroll
  for (int kp = 0; kp < 15; ++kp) {
    u16x8 vn0 = *(const u16x8*)(vrow + kp * 64 + 64);
    u16x8 vn1 = *(const u16x8*)(vrow + kp * 64 + 96);
    bf16x8 a0 = as_bf8(*(const u16x8*)&P[lr][PSWZ(lr, kp * 64 + lg * 8)]);
    bf16x8 a1 = as_bf8(*(const u16x8*)&P[lr][PSWZ(lr, kp * 64 + 32 + lg * 8)]);
    o0 = MFMA16(a0, as_bf8(vc0), o0);
    o1 = MFMA16(a1, as_bf8(vc1), o1);
    vc0 = vn0; vc1 = vn1;
  }
  {
    bf16x8 a0 = as_bf8(*(const u16x8*)&P[lr][PSWZ(lr, 15 * 64 + lg * 8)]);
    bf16x8 a1 = as_bf8(*(const u16x8*)&P[lr][PSWZ(lr, 15 * 64 + 32 + lg * 8)]);
    o0 = MFMA16(a0, as_bf8(vc0), o0);
    o1 = MFMA16(a1, as_bf8(vc1), o1);
  }
  #pragma unroll
  for (int j = 0; j < 5; ++j) {
    u16x8 brv = *(const u16x8*)(rvT + (size_t)(wv_ * 16 + lr) * NRP + j * 32 + lg * 8);
    bf16x8 aa = as_bf8(*(const u16x8*)&S2a2[lr][j * 32 + lg * 8]);
    if (j & 1) o1 = MFMA16(aa, as_bf8(brv), o1);
    else       o0 = MFMA16(aa, as_bf8(brv), o0);
  }

  #pragma unroll
  for (int i = 0; i < 4; ++i) {
    int row = lg * 4 + i;
    float val = (o0[i] + o1[i]) * rowrcp[row];
    int t = q0 + row, cc = h * HD + wv_ * 16 + lr;
    AO[((size_t)(bidx * Tt + t)) * Cc + cc] = f2bf(val);
  }
}

// ---------------------------------------------------------------------------
// Kernel 3: output projection.  AO (bf16 8192x512) @ Wo + bo -> f32 d_out.
// ---------------------------------------------------------------------------
__global__ __launch_bounds__(256) void out_gemm(
    const u16* __restrict__ AO, const u16* __restrict__ WoT,
    const float* __restrict__ bo, float* __restrict__ out)
{
  __shared__ u16 As[64][40];
  __shared__ u16 WTs[64][40];
  const int tid = threadIdx.x;
  const int wv_ = tid >> 6, l = tid & 63, lr = l & 15, lg = l >> 4;
  const int m0 = blockIdx.x * 64, n0 = blockIdx.y * 64;
  const int srow = tid >> 2, scol = (tid & 3) * 8;

  f32x4 acc[4];
  #pragma unroll
  for (int b = 0; b < 4; ++b) acc[b] = (f32x4){0.f, 0.f, 0.f, 0.f};

  for (int k0 = 0; k0 < Cc; k0 += 32) {
    u16x8 av = *(const u16x8*)(AO + (size_t)(m0 + srow) * Cc + k0 + scol);
    *(u16x8*)&As[srow][scol] = av;
    u16x8 wv2 = *(const u16x8*)(WoT + (size_t)(n0 + srow) * Cc + k0 + scol);
    *(u16x8*)&WTs[srow][scol] = wv2;
    __syncthreads();

    bf16x8 a = as_bf8(*(const u16x8*)&As[wv_ * 16 + lr][lg * 8]);
    #pragma unroll
    for (int nt = 0; nt < 4; ++nt) {
      bf16x8 b = as_bf8(*(const u16x8*)&WTs[nt * 16 + lr][lg * 8]);
      acc[nt] = MFMA16(a, b, acc[nt]);
    }
    __syncthreads();
  }

  #pragma unroll
  for (int nt = 0; nt < 4; ++nt) {
    int n = n0 + nt * 16 + lr;
    float bias = bo[n];
    #pragma unroll
    for (int i = 0; i < 4; ++i) {
      int m = m0 + wv_ * 16 + lg * 4 + i;
      out[(size_t)m * Cc + n] = acc[nt][i] + bias;
    }
  }
}

// ---------------------------------------------------------------------------
extern "C" void kernel_launch(void* const* d_in, const int* in_sizes, int n_in,
                              void* d_out, int out_size, void* d_ws, size_t ws_size,
                              hipStream_t stream) {
  const float* x  = (const float*)d_in[0];
  const float* Wq = (const float*)d_in[1];
  const float* bq = (const float*)d_in[2];
  const float* Wk = (const float*)d_in[3];
  const float* bk = (const float*)d_in[4];
  const float* Wv = (const float*)d_in[5];
  const float* bv = (const float*)d_in[6];
  const float* Wo = (const float*)d_in[7];
  const float* bo = (const float*)d_in[8];
  const float* rk = (const float*)d_in[9];
  const float* rv = (const float*)d_in[10];

  const size_t BHTD = (size_t)Bb * Hh * Tt * HD;   // 4,194,304 elements
  const size_t WSZ  = (size_t)Cc * Cc;             // 262,144

  // d_out scratch: Q,K bf16 (fully consumed before out_gemm overwrites).
  u16* Qb = (u16*)d_out;
  u16* Kb = Qb + BHTD;
  // d_ws layout (u16 units): VT | AO | rvT | WqT | WkT | WvT | WoT  (~19MB)
  u16* VT  = (u16*)d_ws;
  u16* AO  = VT + BHTD;
  u16* rvT = AO + BHTD;
  u16* WqT = rvT + (size_t)HD * NRP;
  u16* WkT = WqT + WSZ;
  u16* WvT = WkT + WSZ;
  u16* WoT = WvT + WSZ;
  float* outf = (float*)d_out;

  relv_prep<<<dim3((HD * NRP + 255) / 256), 256, 0, stream>>>(rv, rvT);
  w_prep<<<dim3(256, 4), 256, 0, stream>>>(Wq, Wk, Wv, Wo, WqT, WkT, WvT, WoT);
  qkv_gemm<<<dim3(128, 8), 256, 0, stream>>>(x, WqT, WkT, WvT, bq, bk, bv, Qb, Kb, VT);
  // bh on the FAST grid dim: XCD = bh % 8 (L2 locality for K/V)
  attn_kernel<<<dim3(64, 64), 256, 0, stream>>>(Qb, Kb, VT, rvT, rk, AO);
  out_gemm<<<dim3(128, 8), 256, 0, stream>>>(AO, WoT, bo, outf);
}

// Round 8
// 209.104 us; speedup vs baseline: 1.0739x; 1.0022x over previous
//
#include <hip/hip_runtime.h>
#include <stdint.h>

#define Bb 8
#define Tt 1024
#define Cc 512
#define Hh 8
#define HD 64
#define MREL 68
#define NR 137           // 2*MREL+1
#define NRP 160          // k-extent padded to multiple of 32 for MFMA K-loop
#define A2S 168          // LDS row stride for S2/a2 union
#define SCALE 0.044194173824159216f     // 1/sqrt(512)  (ref scales by embed dim!)
#define KSCL  0.063763016845703125f     // SCALE * log2(e): exp(x)=exp2(x*log2e)

typedef unsigned short u16;
typedef unsigned int u32;
using u16x4  = __attribute__((ext_vector_type(4))) u16;
using u16x8  = __attribute__((ext_vector_type(8))) u16;
using u32x2  = __attribute__((ext_vector_type(2))) u32;
using f32x4  = __attribute__((ext_vector_type(4))) float;
using bf16x8 = __attribute__((ext_vector_type(8))) __bf16;

__device__ __forceinline__ u16 f2bf(float f) {
  u32 u = __builtin_bit_cast(u32, f);
  u += 0x7FFF + ((u >> 16) & 1);       // RTNE
  return (u16)(u >> 16);
}
__device__ __forceinline__ float bf2f(u16 v) {
  return __builtin_bit_cast(float, (u32)v << 16);
}
__device__ __forceinline__ bf16x8 as_bf8(u16x8 v) { return __builtin_bit_cast(bf16x8, v); }
__device__ __forceinline__ float fexp2(float x) {
  float r; asm("v_exp_f32 %0, %1" : "=v"(r) : "v"(x)); return r;
}
__device__ __forceinline__ u32 cvtpk(float lo, float hi) {
  u32 r; asm("v_cvt_pk_bf16_f32 %0, %1, %2" : "=v"(r) : "v"(lo), "v"(hi)); return r;
}

#define MFMA16(a, b, c) __builtin_amdgcn_mfma_f32_16x16x32_bf16((a), (b), (c), 0, 0, 0)
#define PSWZ(row, col) ((col) ^ (((row) & 7) << 3))

// ---------------------------------------------------------------------------
// Kernel 0a: transpose rel_v to bf16 [d][r] with zero pad.
// ---------------------------------------------------------------------------
__global__ __launch_bounds__(256) void relv_prep(
    const float* __restrict__ rel_v, u16* __restrict__ rvT)
{
  int i = blockIdx.x * 256 + threadIdx.x;
  if (i < HD * NRP) {
    int d = i / NRP, r = i - d * NRP;
    rvT[i] = (r < NR) ? f2bf(rel_v[r * HD + d]) : (u16)0;
  }
}

// ---------------------------------------------------------------------------
// Kernel 0b: convert the four 512x512 weights to bf16, TRANSPOSED [n][k].
// ---------------------------------------------------------------------------
__global__ __launch_bounds__(256) void w_prep(
    const float* __restrict__ Wq, const float* __restrict__ Wk,
    const float* __restrict__ Wv, const float* __restrict__ Wo,
    u16* __restrict__ WqT, u16* __restrict__ WkT,
    u16* __restrict__ WvT, u16* __restrict__ WoT)
{
  const float* W = blockIdx.y == 0 ? Wq : blockIdx.y == 1 ? Wk
                  : blockIdx.y == 2 ? Wv : Wo;
  u16* WT = blockIdx.y == 0 ? WqT : blockIdx.y == 1 ? WkT
           : blockIdx.y == 2 ? WvT : WoT;
  int i = blockIdx.x * 256 + threadIdx.x;   // over 512*128
  int n = i >> 7, k4 = (i & 127) * 4;
  u16x4 o;
  #pragma unroll
  for (int j = 0; j < 4; ++j) o[j] = f2bf(W[(size_t)(k4 + j) * Cc + n]);
  *(u16x4*)&WT[(size_t)n * Cc + k4] = o;
}

// ---------------------------------------------------------------------------
// Kernel 1: fused QKV projection.  x (8192x512 f32) @ {Wq,Wk,Wv} + bias.
// Q,K written bf16 (B,H,T,HD); V written TRANSPOSED bf16 (B,H,HD,T).
// ---------------------------------------------------------------------------
__global__ __launch_bounds__(256) void qkv_gemm(
    const float* __restrict__ x,
    const u16* __restrict__ WqT, const u16* __restrict__ WkT,
    const u16* __restrict__ WvT,
    const float* __restrict__ bq, const float* __restrict__ bk,
    const float* __restrict__ bv,
    u16* __restrict__ Qb, u16* __restrict__ Kb, u16* __restrict__ VTb)
{
  __shared__ u16 Xs[64][40];
  __shared__ u16 WTs[3][64][40];

  const u16* Wp[3] = {WqT, WkT, WvT};
  const float* bp[3] = {bq, bk, bv};

  const int tid = threadIdx.x;
  const int wv_ = tid >> 6;
  const int l   = tid & 63;
  const int lr  = l & 15, lg = l >> 4;
  const int m0  = blockIdx.x * 64;
  const int n0  = blockIdx.y * 64;
  const int srow = tid >> 2, scol = (tid & 3) * 8;

  f32x4 acc[3][4];
  #pragma unroll
  for (int a = 0; a < 3; ++a)
    #pragma unroll
    for (int b = 0; b < 4; ++b) acc[a][b] = (f32x4){0.f, 0.f, 0.f, 0.f};

  for (int k0 = 0; k0 < Cc; k0 += 32) {
    {
      const float* xp = x + (size_t)(m0 + srow) * Cc + k0 + scol;
      f32x4 v0 = *(const f32x4*)xp;
      f32x4 v1 = *(const f32x4*)(xp + 4);
      u16x8 o = {f2bf(v0[0]), f2bf(v0[1]), f2bf(v0[2]), f2bf(v0[3]),
                 f2bf(v1[0]), f2bf(v1[1]), f2bf(v1[2]), f2bf(v1[3])};
      *(u16x8*)&Xs[srow][scol] = o;
    }
    #pragma unroll
    for (int q3 = 0; q3 < 3; ++q3) {
      u16x8 w = *(const u16x8*)(Wp[q3] + (size_t)(n0 + srow) * Cc + k0 + scol);
      *(u16x8*)&WTs[q3][srow][scol] = w;
    }
    __syncthreads();

    bf16x8 a = as_bf8(*(const u16x8*)&Xs[wv_ * 16 + lr][lg * 8]);
    #pragma unroll
    for (int q3 = 0; q3 < 3; ++q3) {
      #pragma unroll
      for (int nt = 0; nt < 4; ++nt) {
        bf16x8 b = as_bf8(*(const u16x8*)&WTs[q3][nt * 16 + lr][lg * 8]);
        acc[q3][nt] = MFMA16(a, b, acc[q3][nt]);
      }
    }
    __syncthreads();
  }

  const int bidx = m0 >> 10;
  #pragma unroll
  for (int q3 = 0; q3 < 3; ++q3) {
    #pragma unroll
    for (int nt = 0; nt < 4; ++nt) {
      int n = n0 + nt * 16 + lr;
      int h = n >> 6, d = n & 63;
      float bias = bp[q3][n];
      #pragma unroll
      for (int i = 0; i < 4; ++i) {
        int m = m0 + wv_ * 16 + lg * 4 + i;
        int t = m & (Tt - 1);
        u16 o = f2bf(acc[q3][nt][i] + bias);
        size_t bh = (size_t)(bidx * Hh + h);
        if (q3 == 0)      Qb[(bh * Tt + t) * HD + d] = o;
        else if (q3 == 1) Kb[(bh * Tt + t) * HD + d] = o;
        else              VTb[(bh * HD + d) * Tt + t] = o;
      }
    }
  }
}

// ---------------------------------------------------------------------------
// Kernel 2: relative attention. One block = one (b,h) x 16 q-rows.
// SWAPPED QK^T: MFMA(K,Q) -> lane owns (q=lr fixed, 4 consecutive kc).
// Off-band tiles use per-lane register constants cN/cP (no gather);
// P written via 2x cvt_pk + 1x ds_write_b64.
// ---------------------------------------------------------------------------
__global__ __launch_bounds__(256, 4) void attn_kernel(
    const u16* __restrict__ Qb, const u16* __restrict__ Kb,
    const u16* __restrict__ VTb, const u16* __restrict__ rvT,
    const float* __restrict__ rel_k,
    u16* __restrict__ AO)
{
  __shared__ u16 P[16][1024];      // exp'd probs, bf16, XOR-swizzled cols
  __shared__ u16 S2a2[16][A2S];    // Phase A: S2*KSCL; Phase C+: a2
  __shared__ float red[2][4][16];  // per-wave partials: [0]=rowsum, [1]=s0
  __shared__ float rowrcp[16];

  const int tid = threadIdx.x;
  const int wv_ = tid >> 6, l = tid & 63;
  const int lr = l & 15, lg = l >> 4;
  const int bh = blockIdx.x;           // FAST dim -> XCD = bh % 8
  const int q0 = blockIdx.y * 16;
  const int bidx = bh >> 3, h = bh & 7;

  const u16* Qh = Qb  + (size_t)bh * Tt * HD;
  const u16* Kh = Kb  + (size_t)bh * Tt * HD;
  const u16* Vh = VTb + (size_t)bh * HD * Tt;

  // Q fragments (held for the whole block)
  bf16x8 aQ0 = as_bf8(*(const u16x8*)(Qh + (size_t)(q0 + lr) * HD + lg * 8));
  bf16x8 aQ1 = as_bf8(*(const u16x8*)(Qh + (size_t)(q0 + lr) * HD + 32 + lg * 8));

  // Early K preload for tile 0 (latency hides under the S2 phase)
  const u16* kbase = Kh + (size_t)(wv_ * 16 + lr) * HD + lg * 8;
  u16x8 c0 = *(const u16x8*)(kbase);
  u16x8 c1 = *(const u16x8*)(kbase + 32);

  // S2'' = (Q @ rel_k^T) * SCALE * log2e
  for (int ct = wv_; ct < 9; ct += 4) {
    int r = ct * 16 + lr;
    f32x4 acc = {0.f, 0.f, 0.f, 0.f};
    #pragma unroll
    for (int d0 = 0; d0 < 64; d0 += 32) {
      u16x8 bbits = {0, 0, 0, 0, 0, 0, 0, 0};
      if (r < NR) {
        f32x4 v0 = *(const f32x4*)(rel_k + (size_t)r * HD + d0 + lg * 8);
        f32x4 v1 = *(const f32x4*)(rel_k + (size_t)r * HD + d0 + lg * 8 + 4);
        bbits = (u16x8){f2bf(v0[0]), f2bf(v0[1]), f2bf(v0[2]), f2bf(v0[3]),
                        f2bf(v1[0]), f2bf(v1[1]), f2bf(v1[2]), f2bf(v1[3])};
      }
      acc = MFMA16(d0 ? aQ1 : aQ0, as_bf8(bbits), acc);
    }
    #pragma unroll
    for (int i = 0; i < 4; ++i)
      S2a2[lg * 4 + i][ct * 16 + lr] = f2bf(acc[i] * KSCL);
  }
  __syncthreads();

  // Per-lane constants (q = q0 + lr is FIXED for this lane)
  const int qme = q0 + lr;
  const float cN = bf2f(S2a2[lr][0]);
  const float cP = bf2f(S2a2[lr][NR - 1]);

  // Tile classification (block-uniform):
  //   kt <  lowEnd : all dr <= -68  (use cN, all count toward s0)
  //   kt >= hiStart: all dr >= +68  (use cP)
  //   else         : band (gather + per-element s0 predicate)
  int lowEnd  = (q0 >= 131) ? (((q0 - 131) >> 6) + 1) : 0;
  int hiStart = (q0 + 146) >> 6; if (hiStart > 16) hiStart = 16;

  // Phase A: P = exp2(K·Q*KSCL + rel), per-lane scalar rowsum/s0.
  float ps = 0.f, ps0 = 0.f;
  const int kcb = wv_ * 16 + lg * 4;    // kc base within tile (4 consecutive)

  #pragma unroll
  for (int kt = 0; kt < 16; ++kt) {
    u16x8 n0{}, n1{};
    if (kt < 15) {
      n0 = *(const u16x8*)(kbase + (size_t)(kt + 1) * 64 * HD);
      n1 = *(const u16x8*)(kbase + (size_t)(kt + 1) * 64 * HD + 32);
    }
    f32x4 acc = {0.f, 0.f, 0.f, 0.f};
    acc = MFMA16(as_bf8(c0), aQ0, acc);    // SWAPPED: A=K, B=Q
    acc = MFMA16(as_bf8(c1), aQ1, acc);
    int kc = kt * 64 + kcb;
    float p[4];
    if (kt >= lowEnd && kt < hiStart) {
      // band tile: gather with clamp, per-element s0 predicate
      #pragma unroll
      for (int i = 0; i < 4; ++i) {
        int dr = kc + i - qme;
        dr = dr < -MREL ? -MREL : (dr > MREL ? MREL : dr);
        p[i] = fexp2(fmaf(acc[i], KSCL, bf2f(S2a2[lr][dr + MREL])));
        if (kc + i <= qme - MREL) ps0 += p[i];
      }
      ps += (p[0] + p[1]) + (p[2] + p[3]);
    } else {
      float c = (kt < lowEnd) ? cN : cP;
      #pragma unroll
      for (int i = 0; i < 4; ++i) p[i] = fexp2(fmaf(acc[i], KSCL, c));
      float s4 = (p[0] + p[1]) + (p[2] + p[3]);
      ps += s4;
      if (kt < lowEnd) ps0 += s4;
    }
    u32x2 pw = {cvtpk(p[0], p[1]), cvtpk(p[2], p[3])};
    *(u32x2*)&P[lr][PSWZ(lr, kc)] = pw;    // one ds_write_b64
    if (kt < 15) { c0 = n0; c1 = n1; }
  }

  // Reduce across the 4 lg-groups (2 shuffles), then across waves via LDS.
  ps  += __shfl_xor(ps, 16);  ps  += __shfl_xor(ps, 32);
  ps0 += __shfl_xor(ps0, 16); ps0 += __shfl_xor(ps0, 32);
  if (lg == 0) { red[0][wv_][lr] = ps; red[1][wv_][lr] = ps0; }

  // Early preload of the first V pair (hides under reduction + Phase C)
  const u16* vrow = Vh + (size_t)(wv_ * 16 + lr) * Tt + lg * 8;
  u16x8 vc0 = *(const u16x8*)(vrow);
  u16x8 vc1 = *(const u16x8*)(vrow + 32);

  __syncthreads();

  // Phase C: a2 (overwrites S2''). Interior = shifted copy of P + band sum;
  // a2[0] = s0; a2[136] = rowsum - s0 - band; pads zeroed.
  {
    int row = tid >> 4, c16 = tid & 15;
    int qg = q0 + row;
    float band = 0.f;
    for (int r = 1 + c16; r < NR - 1; r += 16) {
      int k = qg + r - MREL;
      u16 v = (k >= 0 && k < Tt) ? P[row][PSWZ(row, k)] : (u16)0;
      S2a2[row][r] = v;
      band += bf2f(v);
    }
    #pragma unroll
    for (int off = 1; off < 16; off <<= 1) band += __shfl_xor(band, off);
    for (int r = NR + c16; r < NRP; r += 16) S2a2[row][r] = 0;
    if (c16 == 0) {
      float t0 = red[0][0][row] + red[0][1][row] + red[0][2][row] + red[0][3][row];
      float t1 = red[1][0][row] + red[1][1][row] + red[1][2][row] + red[1][3][row];
      S2a2[row][0]      = f2bf(t1);
      S2a2[row][NR - 1] = f2bf(t0 - t1 - band);
      rowrcp[row] = 1.0f / t0;
    }
  }
  __syncthreads();

  // Phase D: O = (P @ V + a2 @ rel_v) * rowrcp. Depth-1 V pipeline, 2 accs.
  f32x4 o0 = {0.f, 0.f, 0.f, 0.f}, o1 = {0.f, 0.f, 0.f, 0.f};
  #pragma unroll
  for (int kp = 0; kp < 15; ++kp) {
    u16x8 vn0 = *(const u16x8*)(vrow + kp * 64 + 64);
    u16x8 vn1 = *(const u16x8*)(vrow + kp * 64 + 96);
    bf16x8 a0 = as_bf8(*(const u16x8*)&P[lr][PSWZ(lr, kp * 64 + lg * 8)]);
    bf16x8 a1 = as_bf8(*(const u16x8*)&P[lr][PSWZ(lr, kp * 64 + 32 + lg * 8)]);
    o0 = MFMA16(a0, as_bf8(vc0), o0);
    o1 = MFMA16(a1, as_bf8(vc1), o1);
    vc0 = vn0; vc1 = vn1;
  }
  {
    bf16x8 a0 = as_bf8(*(const u16x8*)&P[lr][PSWZ(lr, 15 * 64 + lg * 8)]);
    bf16x8 a1 = as_bf8(*(const u16x8*)&P[lr][PSWZ(lr, 15 * 64 + 32 + lg * 8)]);
    o0 = MFMA16(a0, as_bf8(vc0), o0);
    o1 = MFMA16(a1, as_bf8(vc1), o1);
  }
  #pragma unroll
  for (int j = 0; j < 5; ++j) {
    u16x8 brv = *(const u16x8*)(rvT + (size_t)(wv_ * 16 + lr) * NRP + j * 32 + lg * 8);
    bf16x8 aa = as_bf8(*(const u16x8*)&S2a2[lr][j * 32 + lg * 8]);
    if (j & 1) o1 = MFMA16(aa, as_bf8(brv), o1);
    else       o0 = MFMA16(aa, as_bf8(brv), o0);
  }

  #pragma unroll
  for (int i = 0; i < 4; ++i) {
    int row = lg * 4 + i;
    float val = (o0[i] + o1[i]) * rowrcp[row];
    int t = q0 + row, cc = h * HD + wv_ * 16 + lr;
    AO[((size_t)(bidx * Tt + t)) * Cc + cc] = f2bf(val);
  }
}

// ---------------------------------------------------------------------------
// Kernel 3: output projection.  AO (bf16 8192x512) @ Wo + bo -> f32 d_out.
// ---------------------------------------------------------------------------
__global__ __launch_bounds__(256) void out_gemm(
    const u16* __restrict__ AO, const u16* __restrict__ WoT,
    const float* __restrict__ bo, float* __restrict__ out)
{
  __shared__ u16 As[64][40];
  __shared__ u16 WTs[64][40];
  const int tid = threadIdx.x;
  const int wv_ = tid >> 6, l = tid & 63, lr = l & 15, lg = l >> 4;
  const int m0 = blockIdx.x * 64, n0 = blockIdx.y * 64;
  const int srow = tid >> 2, scol = (tid & 3) * 8;

  f32x4 acc[4];
  #pragma unroll
  for (int b = 0; b < 4; ++b) acc[b] = (f32x4){0.f, 0.f, 0.f, 0.f};

  for (int k0 = 0; k0 < Cc; k0 += 32) {
    u16x8 av = *(const u16x8*)(AO + (size_t)(m0 + srow) * Cc + k0 + scol);
    *(u16x8*)&As[srow][scol] = av;
    u16x8 wv2 = *(const u16x8*)(WoT + (size_t)(n0 + srow) * Cc + k0 + scol);
    *(u16x8*)&WTs[srow][scol] = wv2;
    __syncthreads();

    bf16x8 a = as_bf8(*(const u16x8*)&As[wv_ * 16 + lr][lg * 8]);
    #pragma unroll
    for (int nt = 0; nt < 4; ++nt) {
      bf16x8 b = as_bf8(*(const u16x8*)&WTs[nt * 16 + lr][lg * 8]);
      acc[nt] = MFMA16(a, b, acc[nt]);
    }
    __syncthreads();
  }

  #pragma unroll
  for (int nt = 0; nt < 4; ++nt) {
    int n = n0 + nt * 16 + lr;
    float bias = bo[n];
    #pragma unroll
    for (int i = 0; i < 4; ++i) {
      int m = m0 + wv_ * 16 + lg * 4 + i;
      out[(size_t)m * Cc + n] = acc[nt][i] + bias;
    }
  }
}

// ---------------------------------------------------------------------------
extern "C" void kernel_launch(void* const* d_in, const int* in_sizes, int n_in,
                              void* d_out, int out_size, void* d_ws, size_t ws_size,
                              hipStream_t stream) {
  const float* x  = (const float*)d_in[0];
  const float* Wq = (const float*)d_in[1];
  const float* bq = (const float*)d_in[2];
  const float* Wk = (const float*)d_in[3];
  const float* bk = (const float*)d_in[4];
  const float* Wv = (const float*)d_in[5];
  const float* bv = (const float*)d_in[6];
  const float* Wo = (const float*)d_in[7];
  const float* bo = (const float*)d_in[8];
  const float* rk = (const float*)d_in[9];
  const float* rv = (const float*)d_in[10];

  const size_t BHTD = (size_t)Bb * Hh * Tt * HD;   // 4,194,304 elements
  const size_t WSZ  = (size_t)Cc * Cc;             // 262,144

  // d_out scratch: Q,K bf16 (fully consumed before out_gemm overwrites).
  u16* Qb = (u16*)d_out;
  u16* Kb = Qb + BHTD;
  // d_ws layout (u16 units): VT | AO | rvT | WqT | WkT | WvT | WoT  (~19MB)
  u16* VT  = (u16*)d_ws;
  u16* AO  = VT + BHTD;
  u16* rvT = AO + BHTD;
  u16* WqT = rvT + (size_t)HD * NRP;
  u16* WkT = WqT + WSZ;
  u16* WvT = WkT + WSZ;
  u16* WoT = WvT + WSZ;
  float* outf = (float*)d_out;

  relv_prep<<<dim3((HD * NRP + 255) / 256), 256, 0, stream>>>(rv, rvT);
  w_prep<<<dim3(256, 4), 256, 0, stream>>>(Wq, Wk, Wv, Wo, WqT, WkT, WvT, WoT);
  qkv_gemm<<<dim3(128, 8), 256, 0, stream>>>(x, WqT, WkT, WvT, bq, bk, bv, Qb, Kb, VT);
  // bh on the FAST grid dim: XCD = bh % 8 (L2 locality for K/V)
  attn_kernel<<<dim3(64, 64), 256, 0, stream>>>(Qb, Kb, VT, rvT, rk, AO);
  out_gemm<<<dim3(128, 8), 256, 0, stream>>>(AO, WoT, bo, outf);
}